// Round 3
// baseline (1369.139 us; speedup 1.0000x reference)
//
#include <hip/hip_runtime.h>
#include <stdint.h>

#define DI __device__ __forceinline__

constexpr int Bn = 32, Cc = 64, Wn = 96, Hn = 96, Ln = 32, NG = 128, OUTC = 256;
constexpr int SEQ = 96;
constexpr long long NPIX = (long long)Bn * Wn * Hn;   // 294912
constexpr int GRAM_BLOCKS = 128;
constexpr int PIX_PER_BLOCK = (int)(NPIX / GRAM_BLOCKS); // 2304

DI float sigmf(float x) { return 1.0f / (1.0f + __expf(-x)); }
DI float tanhf_(float x) { return 1.0f - 2.0f / (__expf(2.0f * x) + 1.0f); } // NaN-free both tails
DI float bf2f(unsigned short u) { return __uint_as_float(((unsigned)u) << 16); }
DI unsigned short f2bf(float f) {
    unsigned u = __float_as_uint(f);
    u += 0x7FFFu + ((u >> 16) & 1u);   // RNE
    return (unsigned short)(u >> 16);
}
DI float d4(float4 a, float4 b, float acc) {
    acc = fmaf(a.x, b.x, acc); acc = fmaf(a.y, b.y, acc);
    acc = fmaf(a.z, b.z, acc); acc = fmaf(a.w, b.w, acc); return acc;
}

// ---------------------------------------------------------------------------
// Input-projection GEMM (non-recurrent 2/3 of LSTM FLOPs), hoisted out of the
// recurrent loop. Block = (b,q); thread = dg = dir*128+g. Output
// xg[(b*96+q)*96 + t][dg] (bf16, includes bias), t = seq position.
// TRANSPOSE=1: input x [B,C,W,H], q=w, t=h (transpose while staging).
// TRANSPOSE=0: input v [B,H,W,64], q=h, t=w (contiguous slab).
// No per-step barriers / serial sections: pure FMA throughput.
// ---------------------------------------------------------------------------
template<int TRANSPOSE>
__global__ __launch_bounds__(256, 2)
void xg_kernel(const float* __restrict__ in,
               const float* __restrict__ wih_f, const float* __restrict__ bih_f,
               const float* __restrict__ bhh_f,
               const float* __restrict__ wih_b, const float* __restrict__ bih_b,
               const float* __restrict__ bhh_b,
               unsigned short* __restrict__ xg)
{
    __shared__ float xs[SEQ][64];
    const int tid = threadIdx.x;
    const int b = blockIdx.x / 96, q = blockIdx.x % 96;
    const int dir = tid >> 7, g = tid & 127;

    const float* wih = dir ? wih_b : wih_f;
    const float bias = dir ? (bih_b[g] + bhh_b[g]) : (bih_f[g] + bhh_f[g]);

    float4 wi[16];
    const float4* wip = (const float4*)(wih + g * 64);
#pragma unroll
    for (int k = 0; k < 16; ++k) wi[k] = wip[k];

    if (TRANSPOSE) {
        for (int i4 = tid; i4 < 1536; i4 += 256) {
            int c = i4 & 63, h4 = i4 >> 6;
            float4 v = *(const float4*)(in + (((size_t)b * 64 + c) * 96 + q) * 96 + 4 * h4);
            xs[4 * h4 + 0][c] = v.x; xs[4 * h4 + 1][c] = v.y;
            xs[4 * h4 + 2][c] = v.z; xs[4 * h4 + 3][c] = v.w;
        }
    } else {
        const float4* src = (const float4*)(in + (size_t)blockIdx.x * (96 * 64));
        float4* dst = (float4*)&xs[0][0];
        for (int i4 = tid; i4 < 1536; i4 += 256) dst[i4] = src[i4];
    }
    __syncthreads();

    unsigned short* obase = xg + (size_t)blockIdx.x * (96 * 256) + tid;
    for (int t0 = 0; t0 < SEQ; t0 += 2) {
        float a0 = bias, a1 = 0.f, a2 = 0.f, a3 = 0.f;
        float b0 = bias, b1 = 0.f, b2 = 0.f, b3 = 0.f;
        const float4* xt0 = (const float4*)xs[t0];
        const float4* xt1 = (const float4*)xs[t0 + 1];
#pragma unroll
        for (int k = 0; k < 4; ++k) {
            a0 = d4(wi[4 * k + 0], xt0[4 * k + 0], a0);
            a1 = d4(wi[4 * k + 1], xt0[4 * k + 1], a1);
            a2 = d4(wi[4 * k + 2], xt0[4 * k + 2], a2);
            a3 = d4(wi[4 * k + 3], xt0[4 * k + 3], a3);
            b0 = d4(wi[4 * k + 0], xt1[4 * k + 0], b0);
            b1 = d4(wi[4 * k + 1], xt1[4 * k + 1], b1);
            b2 = d4(wi[4 * k + 2], xt1[4 * k + 2], b2);
            b3 = d4(wi[4 * k + 3], xt1[4 * k + 3], b3);
        }
        obase[(size_t)t0 * 256]       = f2bf((a0 + a1) + (a2 + a3));
        obase[(size_t)(t0 + 1) * 256] = f2bf((b0 + b1) + (b2 + b3));
    }
}

// ---------------------------------------------------------------------------
// Recurrent-only BiLSTM. Per step: grec = Whh·h (32 FMAs, weights = 8 float4
// — fits arch VGPRs, unlike the fused kernel's 96 regs that the allocator
// parked in AGPRs, R1/R2 evidence), plus one coalesced bf16 xg load per
// thread (prefetched a full step ahead).
// VERT=1: chain=(b,w), seq h, out f32 v[b,h,w,dir*32+g].
// VERT=0: chain=(b,h), seq w, out bf16 hh[b,h,w,dir*32+g].
// ---------------------------------------------------------------------------
template<int VERT>
__global__ __launch_bounds__(256, 4)
void lstm_rec(const unsigned short* __restrict__ xg,
              const float* __restrict__ whh_f, const float* __restrict__ whh_b,
              void* __restrict__ outv)
{
    __shared__ float hsh[2][32];
    __shared__ float gsh[2][NG];

    const int tid = threadIdx.x;
    const int b = blockIdx.x / 96, q = blockIdx.x % 96;
    const int dir = tid >> 7, g = tid & 127;

    const float* whh = dir ? whh_b : whh_f;
    float4 wh[8];
    const float4* whp = (const float4*)(whh + g * 32);
#pragma unroll
    for (int k = 0; k < 8; ++k) wh[k] = whp[k];

    const bool ist = ((g & 96) == 64);
    const float sc = ist ? 2.0f : 1.0f;
    const float ma = ist ? 2.0f : 1.0f;
    const float ba = ist ? -1.0f : 0.0f;

    if (tid < 64) hsh[tid >> 5][tid & 31] = 0.0f;

    const unsigned short* xbase = xg + (size_t)blockIdx.x * (96 * 256) + tid;
    float xcur = bf2f(xbase[(size_t)(dir ? 95 : 0) * 256]);
    __syncthreads();

    float cst = 0.0f;
    for (int t = 0; t < SEQ; ++t) {
        const int tn = (t < 95) ? t + 1 : 95;
        const float xnext = bf2f(xbase[(size_t)(dir ? 95 - tn : tn) * 256]);

        float a0 = xcur, a1 = 0.f;
        const float4* hv = (const float4*)hsh[dir];
#pragma unroll
        for (int k = 0; k < 4; ++k) {
            a0 = d4(wh[2 * k + 0], hv[2 * k + 0], a0);
            a1 = d4(wh[2 * k + 1], hv[2 * k + 1], a1);
        }
        const float acc = a0 + a1;
        const float e = 1.0f / (1.0f + __expf(-sc * acc));
        gsh[dir][g] = fmaf(e, ma, ba);
        __syncthreads();
        if (g < 32) {
            float ig = gsh[dir][g];
            float fg = gsh[dir][32 + g];
            float gg = gsh[dir][64 + g];
            float og = gsh[dir][96 + g];
            cst = fmaf(fg, cst, ig * gg);
            float hval = og * tanhf_(cst);
            hsh[dir][g] = hval;
            const int te = dir ? 95 - t : t;
            if (VERT) {
                ((float*)outv)[(((size_t)b * 96 + te) * 96 + q) * 64 + dir * 32 + g] = hval;
            } else {
                ((unsigned short*)outv)[(((size_t)b * 96 + q) * 96 + te) * 64 + dir * 32 + g] = f2bf(hval);
            }
        }
        __syncthreads();
        xcur = xnext;
    }
}

// ---------------------------------------------------------------------------
// Partial Gram (64x64) + channel-sum (64) of hh over this block's pixel chunk.
// ---------------------------------------------------------------------------
__global__ __launch_bounds__(256)
void gram_partial(const unsigned short* __restrict__ hh, float* __restrict__ part)
{
    __shared__ float xs[64][64];
    __shared__ float red[4160];
    const int tid = threadIdx.x;
    for (int e = tid; e < 4160; e += 256) red[e] = 0.0f;
    const int lane = tid & 63, wv = tid >> 6;
    const int li = lane >> 3, lj = lane & 7;
    float acc[8][8]; float macc[8];
#pragma unroll
    for (int i = 0; i < 8; ++i) {
        macc[i] = 0.f;
#pragma unroll
        for (int j = 0; j < 8; ++j) acc[i][j] = 0.f;
    }
    const size_t pix0 = (size_t)blockIdx.x * PIX_PER_BLOCK;
    for (int tile = 0; tile < PIX_PER_BLOCK / 64; ++tile) {
        __syncthreads();
        const unsigned short* src = hh + (pix0 + tile * 64) * 64;
#pragma unroll
        for (int r = 0; r < 4; ++r) {
            int idx4 = tid + 256 * r;
            ushort4 v = ((const ushort4*)src)[idx4];
            int fi = idx4 * 4; int px = fi >> 6; int c = fi & 63;
            xs[px][c] = bf2f(v.x); xs[px][c + 1] = bf2f(v.y);
            xs[px][c + 2] = bf2f(v.z); xs[px][c + 3] = bf2f(v.w);
        }
        __syncthreads();
        for (int p = wv * 16; p < wv * 16 + 16; ++p) {
            float4 ra = *(const float4*)&xs[p][8 * li];
            float4 rb = *(const float4*)&xs[p][8 * li + 4];
            float4 ca = *(const float4*)&xs[p][8 * lj];
            float4 cb = *(const float4*)&xs[p][8 * lj + 4];
            float r[8] = {ra.x, ra.y, ra.z, ra.w, rb.x, rb.y, rb.z, rb.w};
            float cl[8] = {ca.x, ca.y, ca.z, ca.w, cb.x, cb.y, cb.z, cb.w};
#pragma unroll
            for (int i = 0; i < 8; ++i) {
#pragma unroll
                for (int j = 0; j < 8; ++j) acc[i][j] = fmaf(r[i], cl[j], acc[i][j]);
            }
            if (lj == 0) {
#pragma unroll
                for (int i = 0; i < 8; ++i) macc[i] += r[i];
            }
        }
    }
    __syncthreads();
#pragma unroll
    for (int i = 0; i < 8; ++i)
#pragma unroll
        for (int j = 0; j < 8; ++j)
            atomicAdd(&red[(8 * li + i) * 64 + 8 * lj + j], acc[i][j]);
    if (lj == 0)
        for (int i = 0; i < 8; ++i) atomicAdd(&red[4096 + 8 * li + i], macc[i]);
    __syncthreads();
    for (int e = tid; e < 4160; e += 256) part[(size_t)blockIdx.x * 4160 + e] = red[e];
}

__global__ void gram_reduce(const float* __restrict__ part, float* __restrict__ M)
{
    int e = blockIdx.x * 256 + threadIdx.x;
    if (e >= 4160) return;
    double s = 0.0;
    for (int p = 0; p < GRAM_BLOCKS; ++p) s += (double)part[(size_t)p * 4160 + e];
    M[e] = (float)s;
}

// Per-output-channel affine coefficients A,B such that out = A*(w_o . u) + B
__global__ __launch_bounds__(256)
void stats_kernel(const float* __restrict__ M, const float* __restrict__ cw,
                  const float* __restrict__ cb, const float* __restrict__ bg,
                  const float* __restrict__ bb,
                  float* __restrict__ Aout, float* __restrict__ Bout)
{
    __shared__ float Ml[4160];
    const int tid = threadIdx.x;
    for (int e = tid; e < 4160; e += 256) Ml[e] = M[e];
    __syncthreads();
    float wr[64];
#pragma unroll
    for (int c = 0; c < 64; ++c) wr[c] = cw[tid * 64 + c];
    float s1 = 0.f;
#pragma unroll
    for (int c = 0; c < 64; ++c) s1 = fmaf(wr[c], Ml[4096 + c], s1);
    float s2 = 0.f;
    for (int c = 0; c < 64; ++c) {
        const float* Mr = &Ml[c * 64];
        float t = 0.f;
#pragma unroll
        for (int d = 0; d < 64; ++d) t = fmaf(wr[d], Mr[d], t);
        s2 = fmaf(wr[c], t, s2);
    }
    const double invN = 1.0 / (double)NPIX;
    double cbo = (double)cb[tid];
    double mu = (double)s1 * invN + cbo;
    double ey2 = (double)s2 * invN + 2.0 * cbo * ((double)s1 * invN) + cbo * cbo;
    double var = ey2 - mu * mu;
    double A = (double)bg[tid] / sqrt(var + 1e-5);
    Aout[tid] = (float)A;
    Bout[tid] = (float)((double)bb[tid] + A * (cbo - mu));
}

// ---------------------------------------------------------------------------
// Fused 1x1 conv + BN apply. Block = (b,w); thread = output channel o.
// ---------------------------------------------------------------------------
__global__ __launch_bounds__(256)
void conv_bn_kernel(const unsigned short* __restrict__ hh, const float* __restrict__ cw,
                    const float* __restrict__ Aarr, const float* __restrict__ Barr,
                    float* __restrict__ out)
{
    __shared__ float us[96][64];
    const int tid = threadIdx.x;
    const int b = blockIdx.x / 96, w = blockIdx.x % 96;
    for (int idx4 = tid; idx4 < 1536; idx4 += 256) {
        int fi = idx4 * 4; int hrow = fi >> 6; int c = fi & 63;
        ushort4 v = *(const ushort4*)(hh + ((size_t)(b * 96 + hrow) * 96 + w) * 64 + c);
        us[hrow][c] = bf2f(v.x); us[hrow][c + 1] = bf2f(v.y);
        us[hrow][c + 2] = bf2f(v.z); us[hrow][c + 3] = bf2f(v.w);
    }
    __syncthreads();
    float4 wreg[16];
    const float4* wp = (const float4*)(cw + tid * 64);
#pragma unroll
    for (int k = 0; k < 16; ++k) wreg[k] = wp[k];
    const float Ao = Aarr[tid], Bo = Barr[tid];
    float* obase = out + (((size_t)b * 256 + tid) * 96 + w) * 96;
    for (int h0 = 0; h0 < 96; h0 += 4) {
        float rv[4];
#pragma unroll
        for (int j = 0; j < 4; ++j) {
            const float4* ur = (const float4*)us[h0 + j];
            float a = 0.f;
#pragma unroll
            for (int k = 0; k < 16; ++k) a = d4(wreg[k], ur[k], a);
            rv[j] = fmaf(Ao, a, Bo);
        }
        float4 res; res.x = rv[0]; res.y = rv[1]; res.z = rv[2]; res.w = rv[3];
        *(float4*)(obase + h0) = res;
    }
}

extern "C" void kernel_launch(void* const* d_in, const int* in_sizes, int n_in,
                              void* d_out, int out_size, void* d_ws, size_t ws_size,
                              hipStream_t stream)
{
    const float* x       = (const float*)d_in[0];
    const float* v_wih_f = (const float*)d_in[1];
    const float* v_whh_f = (const float*)d_in[2];
    const float* v_bih_f = (const float*)d_in[3];
    const float* v_bhh_f = (const float*)d_in[4];
    const float* v_wih_b = (const float*)d_in[5];
    const float* v_whh_b = (const float*)d_in[6];
    const float* v_bih_b = (const float*)d_in[7];
    const float* v_bhh_b = (const float*)d_in[8];
    const float* h_wih_f = (const float*)d_in[9];
    const float* h_whh_f = (const float*)d_in[10];
    const float* h_bih_f = (const float*)d_in[11];
    const float* h_bhh_f = (const float*)d_in[12];
    const float* h_wih_b = (const float*)d_in[13];
    const float* h_whh_b = (const float*)d_in[14];
    const float* h_bih_b = (const float*)d_in[15];
    const float* h_bhh_b = (const float*)d_in[16];
    const float* conv_w  = (const float*)d_in[17];
    const float* conv_b  = (const float*)d_in[18];
    const float* bn_g    = (const float*)d_in[19];
    const float* bn_b    = (const float*)d_in[20];
    float* out = (float*)d_out;

    // d_out (302 MB) doubles as scratch before conv_bn rewrites all of it:
    //   bytes [0, 151 MB): xg buffer (bf16, 294912 x 256) — written/consumed
    //     twice (vertical then horizontal pass)
    //   bytes [226.5, 302 MB): v (f32 [B,H,W,64]) — vertical LSTM output
    const size_t v_elems = (size_t)Bn * Hn * Wn * 64;   // 18,874,368
    float* v_buf = out + ((size_t)out_size - v_elems);
    unsigned short* xgbuf = (unsigned short*)d_out;      // 150,994,944 bytes

    // workspace layout (~40 MB)
    unsigned short* hh = (unsigned short*)d_ws;                       // bf16 [B,H,W,64]
    char* wsb = (char*)d_ws;
    float* part = (float*)(wsb + 37748736);                           // 128 x 4160 f32
    float* M    = (float*)(wsb + 37748736 + 2129920);                 // 4160 f32
    float* Aarr = M + 4160;
    float* Barr = Aarr + 256;

    // vertical pass
    xg_kernel<1><<<3072, 256, 0, stream>>>(x, v_wih_f, v_bih_f, v_bhh_f,
                                           v_wih_b, v_bih_b, v_bhh_b, xgbuf);
    lstm_rec<1><<<3072, 256, 0, stream>>>(xgbuf, v_whh_f, v_whh_b, (void*)v_buf);
    // horizontal pass
    xg_kernel<0><<<3072, 256, 0, stream>>>(v_buf, h_wih_f, h_bih_f, h_bhh_f,
                                           h_wih_b, h_bih_b, h_bhh_b, xgbuf);
    lstm_rec<0><<<3072, 256, 0, stream>>>(xgbuf, h_whh_f, h_whh_b, (void*)hh);
    // conv + BN (affine-folded via Gram-matrix stats)
    gram_partial<<<GRAM_BLOCKS, 256, 0, stream>>>(hh, part);
    gram_reduce<<<17, 256, 0, stream>>>(part, M);
    stats_kernel<<<1, 256, 0, stream>>>(M, conv_w, conv_b, bn_g, bn_b, Aarr, Barr);
    conv_bn_kernel<<<3072, 256, 0, stream>>>(hh, conv_w, Aarr, Barr, out);
}

// Round 4
// 939.661 us; speedup vs baseline: 1.4571x; 1.4571x over previous
//
#include <hip/hip_runtime.h>
#include <stdint.h>

#define DI __device__ __forceinline__

constexpr int Bn = 32, Cc = 64, Wn = 96, Hn = 96, Ln = 32, NG = 128, OUTC = 256;
constexpr int SEQ = 96;
constexpr long long NPIX = (long long)Bn * Wn * Hn;   // 294912
constexpr int GRAM_BLOCKS = 128;
constexpr int PIX_PER_BLOCK = (int)(NPIX / GRAM_BLOCKS); // 2304

typedef __attribute__((ext_vector_type(8))) short bf16x8;
typedef __attribute__((ext_vector_type(4))) float f32x4;

DI float sigmf(float x) { return 1.0f / (1.0f + __expf(-x)); }
DI float tanhf_(float x) { return 1.0f - 2.0f / (__expf(2.0f * x) + 1.0f); } // NaN-free both tails
DI float bf2f(unsigned short u) { return __uint_as_float(((unsigned)u) << 16); }
DI unsigned short f2bf(float f) {
    unsigned u = __float_as_uint(f);
    u += 0x7FFFu + ((u >> 16) & 1u);   // RNE
    return (unsigned short)(u >> 16);
}
DI float d4(float4 a, float4 b, float acc) {
    acc = fmaf(a.x, b.x, acc); acc = fmaf(a.y, b.y, acc);
    acc = fmaf(a.z, b.z, acc); acc = fmaf(a.w, b.w, acc); return acc;
}

// ---------------------------------------------------------------------------
// Input-projection GEMM via MFMA: xg[row t][gate o] = sum_c A[t][c]*W[o][c]+bias
// One block per chain (b,q); A = 96x64 tile, output 96x256.
// R3 post-mortem: the VALU version ran at ~3x its own instruction bound
// (320us); this is matmul-shaped (K=64) -> matrix cores (Guideline 10).
// 512 threads = 8 waves, wave grid 2M x 4N, per-wave 48x64, 16x16x32 bf16.
// A and Wt staged bf16 in LDS with XOR swizzle (byte ^= (row&7)<<4): frag
// reads are 16 rows @ stride 128B = 16-way bank conflict unswizzled (G4/T2).
// TRANSPOSE=1: input x [B,C,W,H], q=w, t=h (transpose in staging).
// TRANSPOSE=0: input v [B,H,W,64] f32, q=h, t=w (contiguous slab).
// ---------------------------------------------------------------------------
template<int TRANSPOSE>
__global__ __launch_bounds__(512, 4)
void xg_kernel(const float* __restrict__ in,
               const float* __restrict__ wih_f, const float* __restrict__ bih_f,
               const float* __restrict__ bhh_f,
               const float* __restrict__ wih_b, const float* __restrict__ bih_b,
               const float* __restrict__ bhh_b,
               unsigned short* __restrict__ xg)
{
    __shared__ alignas(16) unsigned char AsB[96 * 128];    // bf16 A, swizzled
    __shared__ alignas(16) unsigned char WtB[256 * 128];   // bf16 W^T, swizzled
    __shared__ float biasS[256];

    const int tid = threadIdx.x;
    const int b = blockIdx.x / 96, q = blockIdx.x % 96;

    // bias
    if (tid < 256) {
        int o = tid, g = o & 127;
        biasS[o] = (o < 128) ? (bih_f[g] + bhh_f[g]) : (bih_b[g] + bhh_b[g]);
    }
    // Wt[o][c] = wih[o][c], 256 rows x 16 float4 (L2-resident after 1st block)
    for (int i4 = tid; i4 < 4096; i4 += 512) {
        int wrow = i4 >> 4, k4 = i4 & 15;
        const float* wsrc = (wrow < 128 ? wih_f : wih_b) + (size_t)(wrow & 127) * 64 + k4 * 4;
        float4 v = *(const float4*)wsrc;
        ushort4 p; p.x = f2bf(v.x); p.y = f2bf(v.y); p.z = f2bf(v.z); p.w = f2bf(v.w);
        *(ushort4*)(WtB + wrow * 128 + ((k4 * 8) ^ ((wrow & 7) << 4))) = p;
    }
    // A tile
    if (TRANSPOSE) {
        // x[b,c,w=q,h]: float4 along h; lanes sweep h-chunks within a c (coalesced
        // 384B runs), scalar swizzled ushort writes (rows scatter).
        for (int i = tid; i < 1536; i += 512) {
            int c = i / 24, h4 = i - c * 24;
            float4 v = *(const float4*)(in + (((size_t)b * 64 + c) * 96 + q) * 96 + 4 * h4);
            int r0 = 4 * h4;
            float vv[4] = {v.x, v.y, v.z, v.w};
#pragma unroll
            for (int j = 0; j < 4; ++j) {
                int row = r0 + j;
                *(unsigned short*)(AsB + row * 128 + ((c * 2) ^ ((row & 7) << 4))) = f2bf(vv[j]);
            }
        }
    } else {
        for (int i4 = tid; i4 < 1536; i4 += 512) {
            int row = i4 >> 4, k4 = i4 & 15;
            float4 v = *(const float4*)(in + (size_t)blockIdx.x * 6144 + (size_t)i4 * 4);
            ushort4 p; p.x = f2bf(v.x); p.y = f2bf(v.y); p.z = f2bf(v.z); p.w = f2bf(v.w);
            *(ushort4*)(AsB + row * 128 + ((k4 * 8) ^ ((row & 7) << 4))) = p;
        }
    }
    __syncthreads();

    const int wv = tid >> 6, lane = tid & 63;
    const int mbase = (wv >> 2) * 48;       // 0 / 48
    const int nbase = (wv & 3) * 64;        // 0 / 64 / 128 / 192
    const int lrow = lane & 15, lk = (lane >> 4) * 8;

    f32x4 acc[3][4];
#pragma unroll
    for (int m = 0; m < 3; ++m)
#pragma unroll
        for (int n = 0; n < 4; ++n)
            acc[m][n] = (f32x4){0.f, 0.f, 0.f, 0.f};

#pragma unroll
    for (int ks = 0; ks < 2; ++ks) {
        const int kb = (ks * 32 + lk) * 2;    // byte offset of this lane's k-chunk
        bf16x8 am[3], bn[4];
#pragma unroll
        for (int m = 0; m < 3; ++m) {
            int row = mbase + m * 16 + lrow;
            am[m] = *(const bf16x8*)(AsB + row * 128 + (kb ^ ((row & 7) << 4)));
        }
#pragma unroll
        for (int n = 0; n < 4; ++n) {
            int o = nbase + n * 16 + lrow;
            bn[n] = *(const bf16x8*)(WtB + o * 128 + (kb ^ ((o & 7) << 4)));
        }
#pragma unroll
        for (int m = 0; m < 3; ++m)
#pragma unroll
            for (int n = 0; n < 4; ++n)
                acc[m][n] = __builtin_amdgcn_mfma_f32_16x16x32_bf16(am[m], bn[n], acc[m][n], 0, 0, 0);
    }

    unsigned short* ob = xg + (size_t)blockIdx.x * (96 * 256);
#pragma unroll
    for (int n = 0; n < 4; ++n) {
        const int o = nbase + n * 16 + lrow;
        const float bv = biasS[o];
#pragma unroll
        for (int m = 0; m < 3; ++m) {
#pragma unroll
            for (int r = 0; r < 4; ++r) {
                int t = mbase + m * 16 + (lane >> 4) * 4 + r;
                ob[(size_t)t * 256 + o] = f2bf(acc[m][n][r] + bv);
            }
        }
    }
}

// ---------------------------------------------------------------------------
// Recurrent-only BiLSTM. Per step: grec = Whh*h (32 FMAs, weights = 8 float4),
// plus one coalesced bf16 xg load per thread (prefetched a step ahead).
// VERT=1: chain=(b,w), seq h, out f32 v[b,h,w,dir*32+g].
// VERT=0: chain=(b,h), seq w, out bf16 hh[b,h,w,dir*32+g].
// ---------------------------------------------------------------------------
template<int VERT>
__global__ __launch_bounds__(256, 4)
void lstm_rec(const unsigned short* __restrict__ xg,
              const float* __restrict__ whh_f, const float* __restrict__ whh_b,
              void* __restrict__ outv)
{
    __shared__ float hsh[2][32];
    __shared__ float gsh[2][NG];

    const int tid = threadIdx.x;
    const int b = blockIdx.x / 96, q = blockIdx.x % 96;
    const int dir = tid >> 7, g = tid & 127;

    const float* whh = dir ? whh_b : whh_f;
    float4 wh[8];
    const float4* whp = (const float4*)(whh + g * 32);
#pragma unroll
    for (int k = 0; k < 8; ++k) wh[k] = whp[k];

    const bool ist = ((g & 96) == 64);
    const float sc = ist ? 2.0f : 1.0f;
    const float ma = ist ? 2.0f : 1.0f;
    const float ba = ist ? -1.0f : 0.0f;

    if (tid < 64) hsh[tid >> 5][tid & 31] = 0.0f;

    const unsigned short* xbase = xg + (size_t)blockIdx.x * (96 * 256) + tid;
    float xcur = bf2f(xbase[(size_t)(dir ? 95 : 0) * 256]);
    __syncthreads();

    float cst = 0.0f;
    for (int t = 0; t < SEQ; ++t) {
        const int tn = (t < 95) ? t + 1 : 95;
        const float xnext = bf2f(xbase[(size_t)(dir ? 95 - tn : tn) * 256]);

        float a0 = xcur, a1 = 0.f;
        const float4* hv = (const float4*)hsh[dir];
#pragma unroll
        for (int k = 0; k < 4; ++k) {
            a0 = d4(wh[2 * k + 0], hv[2 * k + 0], a0);
            a1 = d4(wh[2 * k + 1], hv[2 * k + 1], a1);
        }
        const float acc = a0 + a1;
        const float e = 1.0f / (1.0f + __expf(-sc * acc));
        gsh[dir][g] = fmaf(e, ma, ba);
        __syncthreads();
        if (g < 32) {
            float ig = gsh[dir][g];
            float fg = gsh[dir][32 + g];
            float gg = gsh[dir][64 + g];
            float og = gsh[dir][96 + g];
            cst = fmaf(fg, cst, ig * gg);
            float hval = og * tanhf_(cst);
            hsh[dir][g] = hval;
            const int te = dir ? 95 - t : t;
            if (VERT) {
                ((float*)outv)[(((size_t)b * 96 + te) * 96 + q) * 64 + dir * 32 + g] = hval;
            } else {
                ((unsigned short*)outv)[(((size_t)b * 96 + q) * 96 + te) * 64 + dir * 32 + g] = f2bf(hval);
            }
        }
        __syncthreads();
        xcur = xnext;
    }
}

// ---------------------------------------------------------------------------
// Partial Gram (64x64) + channel-sum (64) of hh over this block's pixel chunk.
// ---------------------------------------------------------------------------
__global__ __launch_bounds__(256)
void gram_partial(const unsigned short* __restrict__ hh, float* __restrict__ part)
{
    __shared__ float xs[64][64];
    __shared__ float red[4160];
    const int tid = threadIdx.x;
    for (int e = tid; e < 4160; e += 256) red[e] = 0.0f;
    const int lane = tid & 63, wv = tid >> 6;
    const int li = lane >> 3, lj = lane & 7;
    float acc[8][8]; float macc[8];
#pragma unroll
    for (int i = 0; i < 8; ++i) {
        macc[i] = 0.f;
#pragma unroll
        for (int j = 0; j < 8; ++j) acc[i][j] = 0.f;
    }
    const size_t pix0 = (size_t)blockIdx.x * PIX_PER_BLOCK;
    for (int tile = 0; tile < PIX_PER_BLOCK / 64; ++tile) {
        __syncthreads();
        const unsigned short* src = hh + (pix0 + tile * 64) * 64;
#pragma unroll
        for (int r = 0; r < 4; ++r) {
            int idx4 = tid + 256 * r;
            ushort4 v = ((const ushort4*)src)[idx4];
            int fi = idx4 * 4; int px = fi >> 6; int c = fi & 63;
            xs[px][c] = bf2f(v.x); xs[px][c + 1] = bf2f(v.y);
            xs[px][c + 2] = bf2f(v.z); xs[px][c + 3] = bf2f(v.w);
        }
        __syncthreads();
        for (int p = wv * 16; p < wv * 16 + 16; ++p) {
            float4 ra = *(const float4*)&xs[p][8 * li];
            float4 rb = *(const float4*)&xs[p][8 * li + 4];
            float4 ca = *(const float4*)&xs[p][8 * lj];
            float4 cb = *(const float4*)&xs[p][8 * lj + 4];
            float r[8] = {ra.x, ra.y, ra.z, ra.w, rb.x, rb.y, rb.z, rb.w};
            float cl[8] = {ca.x, ca.y, ca.z, ca.w, cb.x, cb.y, cb.z, cb.w};
#pragma unroll
            for (int i = 0; i < 8; ++i) {
#pragma unroll
                for (int j = 0; j < 8; ++j) acc[i][j] = fmaf(r[i], cl[j], acc[i][j]);
            }
            if (lj == 0) {
#pragma unroll
                for (int i = 0; i < 8; ++i) macc[i] += r[i];
            }
        }
    }
    __syncthreads();
#pragma unroll
    for (int i = 0; i < 8; ++i)
#pragma unroll
        for (int j = 0; j < 8; ++j)
            atomicAdd(&red[(8 * li + i) * 64 + 8 * lj + j], acc[i][j]);
    if (lj == 0)
        for (int i = 0; i < 8; ++i) atomicAdd(&red[4096 + 8 * li + i], macc[i]);
    __syncthreads();
    for (int e = tid; e < 4160; e += 256) part[(size_t)blockIdx.x * 4160 + e] = red[e];
}

__global__ void gram_reduce(const float* __restrict__ part, float* __restrict__ M)
{
    int e = blockIdx.x * 256 + threadIdx.x;
    if (e >= 4160) return;
    double s = 0.0;
    for (int p = 0; p < GRAM_BLOCKS; ++p) s += (double)part[(size_t)p * 4160 + e];
    M[e] = (float)s;
}

// Per-output-channel affine coefficients A,B such that out = A*(w_o . u) + B
__global__ __launch_bounds__(256)
void stats_kernel(const float* __restrict__ M, const float* __restrict__ cw,
                  const float* __restrict__ cb, const float* __restrict__ bg,
                  const float* __restrict__ bb,
                  float* __restrict__ Aout, float* __restrict__ Bout)
{
    __shared__ float Ml[4160];
    const int tid = threadIdx.x;
    for (int e = tid; e < 4160; e += 256) Ml[e] = M[e];
    __syncthreads();
    float wr[64];
#pragma unroll
    for (int c = 0; c < 64; ++c) wr[c] = cw[tid * 64 + c];
    float s1 = 0.f;
#pragma unroll
    for (int c = 0; c < 64; ++c) s1 = fmaf(wr[c], Ml[4096 + c], s1);
    float s2 = 0.f;
    for (int c = 0; c < 64; ++c) {
        const float* Mr = &Ml[c * 64];
        float t = 0.f;
#pragma unroll
        for (int d = 0; d < 64; ++d) t = fmaf(wr[d], Mr[d], t);
        s2 = fmaf(wr[c], t, s2);
    }
    const double invN = 1.0 / (double)NPIX;
    double cbo = (double)cb[tid];
    double mu = (double)s1 * invN + cbo;
    double ey2 = (double)s2 * invN + 2.0 * cbo * ((double)s1 * invN) + cbo * cbo;
    double var = ey2 - mu * mu;
    double A = (double)bg[tid] / sqrt(var + 1e-5);
    Aout[tid] = (float)A;
    Bout[tid] = (float)((double)bb[tid] + A * (cbo - mu));
}

// ---------------------------------------------------------------------------
// Fused 1x1 conv + BN apply. Block = (b,w); thread = output channel o.
// ---------------------------------------------------------------------------
__global__ __launch_bounds__(256)
void conv_bn_kernel(const unsigned short* __restrict__ hh, const float* __restrict__ cw,
                    const float* __restrict__ Aarr, const float* __restrict__ Barr,
                    float* __restrict__ out)
{
    __shared__ float us[96][64];
    const int tid = threadIdx.x;
    const int b = blockIdx.x / 96, w = blockIdx.x % 96;
    for (int idx4 = tid; idx4 < 1536; idx4 += 256) {
        int fi = idx4 * 4; int hrow = fi >> 6; int c = fi & 63;
        ushort4 v = *(const ushort4*)(hh + ((size_t)(b * 96 + hrow) * 96 + w) * 64 + c);
        us[hrow][c] = bf2f(v.x); us[hrow][c + 1] = bf2f(v.y);
        us[hrow][c + 2] = bf2f(v.z); us[hrow][c + 3] = bf2f(v.w);
    }
    __syncthreads();
    float4 wreg[16];
    const float4* wp = (const float4*)(cw + tid * 64);
#pragma unroll
    for (int k = 0; k < 16; ++k) wreg[k] = wp[k];
    const float Ao = Aarr[tid], Bo = Barr[tid];
    float* obase = out + (((size_t)b * 256 + tid) * 96 + w) * 96;
    for (int h0 = 0; h0 < 96; h0 += 4) {
        float rv[4];
#pragma unroll
        for (int j = 0; j < 4; ++j) {
            const float4* ur = (const float4*)us[h0 + j];
            float a = 0.f;
#pragma unroll
            for (int k = 0; k < 16; ++k) a = d4(wreg[k], ur[k], a);
            rv[j] = fmaf(Ao, a, Bo);
        }
        float4 res; res.x = rv[0]; res.y = rv[1]; res.z = rv[2]; res.w = rv[3];
        *(float4*)(obase + h0) = res;
    }
}

extern "C" void kernel_launch(void* const* d_in, const int* in_sizes, int n_in,
                              void* d_out, int out_size, void* d_ws, size_t ws_size,
                              hipStream_t stream)
{
    const float* x       = (const float*)d_in[0];
    const float* v_wih_f = (const float*)d_in[1];
    const float* v_whh_f = (const float*)d_in[2];
    const float* v_bih_f = (const float*)d_in[3];
    const float* v_bhh_f = (const float*)d_in[4];
    const float* v_wih_b = (const float*)d_in[5];
    const float* v_whh_b = (const float*)d_in[6];
    const float* v_bih_b = (const float*)d_in[7];
    const float* v_bhh_b = (const float*)d_in[8];
    const float* h_wih_f = (const float*)d_in[9];
    const float* h_whh_f = (const float*)d_in[10];
    const float* h_bih_f = (const float*)d_in[11];
    const float* h_bhh_f = (const float*)d_in[12];
    const float* h_wih_b = (const float*)d_in[13];
    const float* h_whh_b = (const float*)d_in[14];
    const float* h_bih_b = (const float*)d_in[15];
    const float* h_bhh_b = (const float*)d_in[16];
    const float* conv_w  = (const float*)d_in[17];
    const float* conv_b  = (const float*)d_in[18];
    const float* bn_g    = (const float*)d_in[19];
    const float* bn_b    = (const float*)d_in[20];
    float* out = (float*)d_out;

    // d_out (302 MB) doubles as scratch before conv_bn rewrites all of it:
    //   bytes [0, 151 MB): xg buffer (bf16, 294912 x 256)
    //   bytes [226.5, 302 MB): v (f32 [B,H,W,64]) — vertical LSTM output
    const size_t v_elems = (size_t)Bn * Hn * Wn * 64;   // 18,874,368
    float* v_buf = out + ((size_t)out_size - v_elems);
    unsigned short* xgbuf = (unsigned short*)d_out;      // 150,994,944 bytes

    // workspace layout (~40 MB)
    unsigned short* hh = (unsigned short*)d_ws;                       // bf16 [B,H,W,64]
    char* wsb = (char*)d_ws;
    float* part = (float*)(wsb + 37748736);                           // 128 x 4160 f32
    float* M    = (float*)(wsb + 37748736 + 2129920);                 // 4160 f32
    float* Aarr = M + 4160;
    float* Barr = Aarr + 256;

    // vertical pass
    xg_kernel<1><<<3072, 512, 0, stream>>>(x, v_wih_f, v_bih_f, v_bhh_f,
                                           v_wih_b, v_bih_b, v_bhh_b, xgbuf);
    lstm_rec<1><<<3072, 256, 0, stream>>>(xgbuf, v_whh_f, v_whh_b, (void*)v_buf);
    // horizontal pass
    xg_kernel<0><<<3072, 512, 0, stream>>>(v_buf, h_wih_f, h_bih_f, h_bhh_f,
                                           h_wih_b, h_bih_b, h_bhh_b, xgbuf);
    lstm_rec<0><<<3072, 256, 0, stream>>>(xgbuf, h_whh_f, h_whh_b, (void*)hh);
    // conv + BN (affine-folded via Gram-matrix stats)
    gram_partial<<<GRAM_BLOCKS, 256, 0, stream>>>(hh, part);
    gram_reduce<<<17, 256, 0, stream>>>(part, M);
    stats_kernel<<<1, 256, 0, stream>>>(M, conv_w, conv_b, bn_g, bn_b, Aarr, Barr);
    conv_bn_kernel<<<3072, 256, 0, stream>>>(hh, conv_w, Aarr, Barr, out);
}

// Round 5
// 853.433 us; speedup vs baseline: 1.6043x; 1.1010x over previous
//
#include <hip/hip_runtime.h>
#include <stdint.h>

#define DI __device__ __forceinline__

constexpr int Bn = 32, Cc = 64, Wn = 96, Hn = 96, Ln = 32, NG = 128, OUTC = 256;
constexpr int SEQ = 96;
constexpr long long NPIX = (long long)Bn * Wn * Hn;   // 294912
constexpr int GRAM_BLOCKS = 128;
constexpr int PIX_PER_BLOCK = (int)(NPIX / GRAM_BLOCKS); // 2304

typedef __attribute__((ext_vector_type(8))) short bf16x8;
typedef __attribute__((ext_vector_type(4))) float f32x4;

DI float sigmf(float x) { return 1.0f / (1.0f + __expf(-x)); }
DI float tanhf_(float x) { return 1.0f - 2.0f / (__expf(2.0f * x) + 1.0f); } // NaN-free both tails
DI float bf2f(unsigned short u) { return __uint_as_float(((unsigned)u) << 16); }
DI unsigned short f2bf(float f) {
    unsigned u = __float_as_uint(f);
    u += 0x7FFFu + ((u >> 16) & 1u);   // RNE
    return (unsigned short)(u >> 16);
}
DI float d4(float4 a, float4 b, float acc) {
    acc = fmaf(a.x, b.x, acc); acc = fmaf(a.y, b.y, acc);
    acc = fmaf(a.z, b.z, acc); acc = fmaf(a.w, b.w, acc); return acc;
}

// ---------------------------------------------------------------------------
// Input-projection GEMM via MFMA (passed R4, absmax 0.039).
// One block per chain (b,q); A = 96x64 tile, output 96x256 bf16 xg.
// ---------------------------------------------------------------------------
template<int TRANSPOSE>
__global__ __launch_bounds__(512, 4)
void xg_kernel(const float* __restrict__ in,
               const float* __restrict__ wih_f, const float* __restrict__ bih_f,
               const float* __restrict__ bhh_f,
               const float* __restrict__ wih_b, const float* __restrict__ bih_b,
               const float* __restrict__ bhh_b,
               unsigned short* __restrict__ xg)
{
    __shared__ alignas(16) unsigned char AsB[96 * 128];    // bf16 A, swizzled
    __shared__ alignas(16) unsigned char WtB[256 * 128];   // bf16 W^T, swizzled
    __shared__ float biasS[256];

    const int tid = threadIdx.x;
    const int b = blockIdx.x / 96, q = blockIdx.x % 96;

    if (tid < 256) {
        int o = tid, g = o & 127;
        biasS[o] = (o < 128) ? (bih_f[g] + bhh_f[g]) : (bih_b[g] + bhh_b[g]);
    }
    for (int i4 = tid; i4 < 4096; i4 += 512) {
        int wrow = i4 >> 4, k4 = i4 & 15;
        const float* wsrc = (wrow < 128 ? wih_f : wih_b) + (size_t)(wrow & 127) * 64 + k4 * 4;
        float4 v = *(const float4*)wsrc;
        ushort4 p; p.x = f2bf(v.x); p.y = f2bf(v.y); p.z = f2bf(v.z); p.w = f2bf(v.w);
        *(ushort4*)(WtB + wrow * 128 + ((k4 * 8) ^ ((wrow & 7) << 4))) = p;
    }
    if (TRANSPOSE) {
        for (int i = tid; i < 1536; i += 512) {
            int c = i / 24, h4 = i - c * 24;
            float4 v = *(const float4*)(in + (((size_t)b * 64 + c) * 96 + q) * 96 + 4 * h4);
            int r0 = 4 * h4;
            float vv[4] = {v.x, v.y, v.z, v.w};
#pragma unroll
            for (int j = 0; j < 4; ++j) {
                int row = r0 + j;
                *(unsigned short*)(AsB + row * 128 + ((c * 2) ^ ((row & 7) << 4))) = f2bf(vv[j]);
            }
        }
    } else {
        for (int i4 = tid; i4 < 1536; i4 += 512) {
            int row = i4 >> 4, k4 = i4 & 15;
            float4 v = *(const float4*)(in + (size_t)blockIdx.x * 6144 + (size_t)i4 * 4);
            ushort4 p; p.x = f2bf(v.x); p.y = f2bf(v.y); p.z = f2bf(v.z); p.w = f2bf(v.w);
            *(ushort4*)(AsB + row * 128 + ((k4 * 8) ^ ((row & 7) << 4))) = p;
        }
    }
    __syncthreads();

    const int wv = tid >> 6, lane = tid & 63;
    const int mbase = (wv >> 2) * 48;
    const int nbase = (wv & 3) * 64;
    const int lrow = lane & 15, lk = (lane >> 4) * 8;

    f32x4 acc[3][4];
#pragma unroll
    for (int m = 0; m < 3; ++m)
#pragma unroll
        for (int n = 0; n < 4; ++n)
            acc[m][n] = (f32x4){0.f, 0.f, 0.f, 0.f};

#pragma unroll
    for (int ks = 0; ks < 2; ++ks) {
        const int kb = (ks * 32 + lk) * 2;
        bf16x8 am[3], bn[4];
#pragma unroll
        for (int m = 0; m < 3; ++m) {
            int row = mbase + m * 16 + lrow;
            am[m] = *(const bf16x8*)(AsB + row * 128 + (kb ^ ((row & 7) << 4)));
        }
#pragma unroll
        for (int n = 0; n < 4; ++n) {
            int o = nbase + n * 16 + lrow;
            bn[n] = *(const bf16x8*)(WtB + o * 128 + (kb ^ ((o & 7) << 4)));
        }
#pragma unroll
        for (int m = 0; m < 3; ++m)
#pragma unroll
            for (int n = 0; n < 4; ++n)
                acc[m][n] = __builtin_amdgcn_mfma_f32_16x16x32_bf16(am[m], bn[n], acc[m][n], 0, 0, 0);
    }

    unsigned short* ob = xg + (size_t)blockIdx.x * (96 * 256);
#pragma unroll
    for (int n = 0; n < 4; ++n) {
        const int o = nbase + n * 16 + lrow;
        const float bv = biasS[o];
#pragma unroll
        for (int m = 0; m < 3; ++m) {
#pragma unroll
            for (int r = 0; r < 4; ++r) {
                int t = mbase + m * 16 + (lane >> 4) * 4 + r;
                ob[(size_t)t * 256 + o] = f2bf(acc[m][n][r] + bv);
            }
        }
    }
}

// ---------------------------------------------------------------------------
// Recurrent-only BiLSTM, one WAVE per (chain, dir): no __syncthreads at all
// (R2-R4: 96 steps x 2 block barriers + 64/256-lane serial section dominated).
// Lane owns 2 gate rows: gA = lane (i|f), gB = lane+64 (g|o). Per step:
// 32 __shfl h-broadcasts feeding 2x32 FMAs, activation on all 64 lanes,
// i/g <-> f/o exchange via __shfl_xor(.,32), cell update on lanes 0-31.
// ---------------------------------------------------------------------------
template<int VERT>
__global__ __launch_bounds__(256, 4)
void lstm_rec(const unsigned short* __restrict__ xg,
              const float* __restrict__ whh_f, const float* __restrict__ whh_b,
              void* __restrict__ outv)
{
    const int tid = threadIdx.x;
    const int wv = tid >> 6, lane = tid & 63;
    const int unit = blockIdx.x * 4 + wv;      // [0, 6144)
    const int chain = unit >> 1, dir = unit & 1;
    const int b = chain / 96, q = chain % 96;

    const float* whh = dir ? whh_b : whh_f;
    float whA[32], whB[32];
    {
        const float4* pa = (const float4*)(whh + (size_t)lane * 32);
        const float4* pb = (const float4*)(whh + (size_t)(lane + 64) * 32);
#pragma unroll
        for (int k = 0; k < 8; ++k) {
            float4 a = pa[k], v = pb[k];
            whA[4 * k + 0] = a.x; whA[4 * k + 1] = a.y; whA[4 * k + 2] = a.z; whA[4 * k + 3] = a.w;
            whB[4 * k + 0] = v.x; whB[4 * k + 1] = v.y; whB[4 * k + 2] = v.z; whB[4 * k + 3] = v.w;
        }
    }
    // B-gate activation: lanes<32 = g-gate (tanh = 2*sigm(2x)-1), >=32 = o (sigm)
    const bool istB = (lane < 32);
    const float scB = istB ? 2.f : 1.f, maB = istB ? 2.f : 1.f, baB = istB ? -1.f : 0.f;

    const unsigned short* xrow = xg + (size_t)chain * (96 * 256) + dir * 128;
    const int te0 = dir ? 95 : 0;
    float xA = bf2f(xrow[(size_t)te0 * 256 + lane]);
    float xB = bf2f(xrow[(size_t)te0 * 256 + 64 + lane]);

    float hval = 0.f, cst = 0.f;
    for (int t = 0; t < SEQ; ++t) {
        const int te = dir ? 95 - t : t;
        const int tn = (t < 95) ? (dir ? te - 1 : te + 1) : te;
        const float xA_n = bf2f(xrow[(size_t)tn * 256 + lane]);
        const float xB_n = bf2f(xrow[(size_t)tn * 256 + 64 + lane]);

        float aA0 = xA, aA1 = 0.f, aB0 = xB, aB1 = 0.f;
#pragma unroll
        for (int j = 0; j < 32; j += 2) {
            float h0 = __shfl(hval, j);
            float h1 = __shfl(hval, j + 1);
            aA0 = fmaf(whA[j], h0, aA0);
            aB0 = fmaf(whB[j], h0, aB0);
            aA1 = fmaf(whA[j + 1], h1, aA1);
            aB1 = fmaf(whB[j + 1], h1, aB1);
        }
        const float aA = aA0 + aA1, aB = aB0 + aB1;
        const float actA = 1.f / (1.f + __expf(-aA));          // i (l<32) | f (l>=32)
        const float eB = 1.f / (1.f + __expf(-scB * aB));
        const float actB = fmaf(eB, maB, baB);                 // g (l<32) | o (l>=32)
        const float fo = __shfl_xor(actA, 32);                 // f (for l<32)
        const float oo = __shfl_xor(actB, 32);                 // o (for l<32)
        cst = fmaf(fo, cst, actA * actB);                      // c = f*c + i*g  (l<32)
        const float hnew = oo * tanhf_(cst);
        hval = hnew;                                           // lanes>=32: garbage, never read
        if (lane < 32) {
            if (VERT) ((float*)outv)[(((size_t)b * 96 + te) * 96 + q) * 64 + dir * 32 + lane] = hnew;
            else ((unsigned short*)outv)[(((size_t)b * 96 + q) * 96 + te) * 64 + dir * 32 + lane] = f2bf(hnew);
        }
        xA = xA_n; xB = xB_n;
    }
}

// ---------------------------------------------------------------------------
// Partial Gram (64x64) + channel-sum (64) of hh over this block's pixel chunk.
// ---------------------------------------------------------------------------
__global__ __launch_bounds__(256)
void gram_partial(const unsigned short* __restrict__ hh, float* __restrict__ part)
{
    __shared__ float xs[64][64];
    __shared__ float red[4160];
    const int tid = threadIdx.x;
    for (int e = tid; e < 4160; e += 256) red[e] = 0.0f;
    const int lane = tid & 63, wv = tid >> 6;
    const int li = lane >> 3, lj = lane & 7;
    float acc[8][8]; float macc[8];
#pragma unroll
    for (int i = 0; i < 8; ++i) {
        macc[i] = 0.f;
#pragma unroll
        for (int j = 0; j < 8; ++j) acc[i][j] = 0.f;
    }
    const size_t pix0 = (size_t)blockIdx.x * PIX_PER_BLOCK;
    for (int tile = 0; tile < PIX_PER_BLOCK / 64; ++tile) {
        __syncthreads();
        const unsigned short* src = hh + (pix0 + tile * 64) * 64;
#pragma unroll
        for (int r = 0; r < 4; ++r) {
            int idx4 = tid + 256 * r;
            ushort4 v = ((const ushort4*)src)[idx4];
            int fi = idx4 * 4; int px = fi >> 6; int c = fi & 63;
            xs[px][c] = bf2f(v.x); xs[px][c + 1] = bf2f(v.y);
            xs[px][c + 2] = bf2f(v.z); xs[px][c + 3] = bf2f(v.w);
        }
        __syncthreads();
        for (int p = wv * 16; p < wv * 16 + 16; ++p) {
            float4 ra = *(const float4*)&xs[p][8 * li];
            float4 rb = *(const float4*)&xs[p][8 * li + 4];
            float4 ca = *(const float4*)&xs[p][8 * lj];
            float4 cb = *(const float4*)&xs[p][8 * lj + 4];
            float r[8] = {ra.x, ra.y, ra.z, ra.w, rb.x, rb.y, rb.z, rb.w};
            float cl[8] = {ca.x, ca.y, ca.z, ca.w, cb.x, cb.y, cb.z, cb.w};
#pragma unroll
            for (int i = 0; i < 8; ++i) {
#pragma unroll
                for (int j = 0; j < 8; ++j) acc[i][j] = fmaf(r[i], cl[j], acc[i][j]);
            }
            if (lj == 0) {
#pragma unroll
                for (int i = 0; i < 8; ++i) macc[i] += r[i];
            }
        }
    }
    __syncthreads();
#pragma unroll
    for (int i = 0; i < 8; ++i)
#pragma unroll
        for (int j = 0; j < 8; ++j)
            atomicAdd(&red[(8 * li + i) * 64 + 8 * lj + j], acc[i][j]);
    if (lj == 0)
        for (int i = 0; i < 8; ++i) atomicAdd(&red[4096 + 8 * li + i], macc[i]);
    __syncthreads();
    for (int e = tid; e < 4160; e += 256) part[(size_t)blockIdx.x * 4160 + e] = red[e];
}

__global__ void gram_reduce(const float* __restrict__ part, float* __restrict__ M)
{
    int e = blockIdx.x * 256 + threadIdx.x;
    if (e >= 4160) return;
    double s = 0.0;
    for (int p = 0; p < GRAM_BLOCKS; ++p) s += (double)part[(size_t)p * 4160 + e];
    M[e] = (float)s;
}

// Per-output-channel affine coefficients A,B such that out = A*(w_o . u) + B.
// Weights rounded through bf16 so A/B match the bf16-MFMA conv exactly.
__global__ __launch_bounds__(256)
void stats_kernel(const float* __restrict__ M, const float* __restrict__ cw,
                  const float* __restrict__ cb, const float* __restrict__ bg,
                  const float* __restrict__ bb,
                  float* __restrict__ Aout, float* __restrict__ Bout)
{
    __shared__ float Ml[4160];
    const int tid = threadIdx.x;
    for (int e = tid; e < 4160; e += 256) Ml[e] = M[e];
    __syncthreads();
    float wr[64];
#pragma unroll
    for (int c = 0; c < 64; ++c) wr[c] = bf2f(f2bf(cw[tid * 64 + c]));
    float s1 = 0.f;
#pragma unroll
    for (int c = 0; c < 64; ++c) s1 = fmaf(wr[c], Ml[4096 + c], s1);
    float s2 = 0.f;
    for (int c = 0; c < 64; ++c) {
        const float* Mr = &Ml[c * 64];
        float t = 0.f;
#pragma unroll
        for (int d = 0; d < 64; ++d) t = fmaf(wr[d], Mr[d], t);
        s2 = fmaf(wr[c], t, s2);
    }
    const double invN = 1.0 / (double)NPIX;
    double cbo = (double)cb[tid];
    double mu = (double)s1 * invN + cbo;
    double ey2 = (double)s2 * invN + 2.0 * cbo * ((double)s1 * invN) + cbo * cbo;
    double var = ey2 - mu * mu;
    double A = (double)bg[tid] / sqrt(var + 1e-5);
    Aout[tid] = (float)A;
    Bout[tid] = (float)((double)bb[tid] + A * (cbo - mu));
}

// ---------------------------------------------------------------------------
// Fused 1x1 conv + BN apply via MFMA. Block = (b,w): D[96 h][256 o] =
// U[96x64] x Wt^T. R4 counters: old VALU version wrote 733 MB for a 302 MB
// output (scattered 16B stores, 2.4x amplification) at 54% VALUBusy. MFMA
// C-layout (col=o=lane&15, row=h=(lane>>4)*4+r) -> each lane stores float4
// along h; the 4 lane-groups of one o-column cover a full 64B line.
// ---------------------------------------------------------------------------
__global__ __launch_bounds__(512, 2)
void conv_bn_kernel(const unsigned short* __restrict__ hh, const float* __restrict__ cw,
                    const float* __restrict__ Aarr, const float* __restrict__ Barr,
                    float* __restrict__ out)
{
    __shared__ alignas(16) unsigned char UsB[96 * 128];    // bf16 U, swizzled
    __shared__ alignas(16) unsigned char WtB[256 * 128];   // bf16 conv W, swizzled

    const int tid = threadIdx.x;
    const int b = blockIdx.x / 96, w = blockIdx.x % 96;

    for (int i4 = tid; i4 < 4096; i4 += 512) {
        int wrow = i4 >> 4, k4 = i4 & 15;
        float4 v = *(const float4*)(cw + (size_t)wrow * 64 + k4 * 4);
        ushort4 p; p.x = f2bf(v.x); p.y = f2bf(v.y); p.z = f2bf(v.z); p.w = f2bf(v.w);
        *(ushort4*)(WtB + wrow * 128 + ((k4 * 8) ^ ((wrow & 7) << 4))) = p;
    }
    for (int i = tid; i < 1536; i += 512) {
        int row = i >> 4, k4 = i & 15;   // row = h
        ushort4 p = *(const ushort4*)(hh + (((size_t)b * 96 + row) * 96 + w) * 64 + k4 * 4);
        *(ushort4*)(UsB + row * 128 + ((k4 * 8) ^ ((row & 7) << 4))) = p;
    }
    __syncthreads();

    const int wv = tid >> 6, lane = tid & 63;
    const int mbase = (wv >> 2) * 48, nbase = (wv & 3) * 64;
    const int lrow = lane & 15, lk = (lane >> 4) * 8;

    f32x4 acc[3][4];
#pragma unroll
    for (int m = 0; m < 3; ++m)
#pragma unroll
        for (int n = 0; n < 4; ++n)
            acc[m][n] = (f32x4){0.f, 0.f, 0.f, 0.f};

#pragma unroll
    for (int ks = 0; ks < 2; ++ks) {
        const int kb = (ks * 32 + lk) * 2;
        bf16x8 am[3], bn[4];
#pragma unroll
        for (int m = 0; m < 3; ++m) {
            int row = mbase + m * 16 + lrow;
            am[m] = *(const bf16x8*)(UsB + row * 128 + (kb ^ ((row & 7) << 4)));
        }
#pragma unroll
        for (int n = 0; n < 4; ++n) {
            int o = nbase + n * 16 + lrow;
            bn[n] = *(const bf16x8*)(WtB + o * 128 + (kb ^ ((o & 7) << 4)));
        }
#pragma unroll
        for (int m = 0; m < 3; ++m)
#pragma unroll
            for (int n = 0; n < 4; ++n)
                acc[m][n] = __builtin_amdgcn_mfma_f32_16x16x32_bf16(am[m], bn[n], acc[m][n], 0, 0, 0);
    }

    const int hbase0 = (lane >> 4) * 4;
#pragma unroll
    for (int n = 0; n < 4; ++n) {
        const int o = nbase + n * 16 + lrow;
        const float Ao = Aarr[o], Bo = Barr[o];
        float* obase = out + (((size_t)b * 256 + o) * 96 + w) * 96;
#pragma unroll
        for (int m = 0; m < 3; ++m) {
            const int h0 = mbase + m * 16 + hbase0;
            float4 res;
            res.x = fmaf(Ao, acc[m][n][0], Bo);
            res.y = fmaf(Ao, acc[m][n][1], Bo);
            res.z = fmaf(Ao, acc[m][n][2], Bo);
            res.w = fmaf(Ao, acc[m][n][3], Bo);
            *(float4*)(obase + h0) = res;
        }
    }
}

extern "C" void kernel_launch(void* const* d_in, const int* in_sizes, int n_in,
                              void* d_out, int out_size, void* d_ws, size_t ws_size,
                              hipStream_t stream)
{
    const float* x       = (const float*)d_in[0];
    const float* v_wih_f = (const float*)d_in[1];
    const float* v_whh_f = (const float*)d_in[2];
    const float* v_bih_f = (const float*)d_in[3];
    const float* v_bhh_f = (const float*)d_in[4];
    const float* v_wih_b = (const float*)d_in[5];
    const float* v_whh_b = (const float*)d_in[6];
    const float* v_bih_b = (const float*)d_in[7];
    const float* v_bhh_b = (const float*)d_in[8];
    const float* h_wih_f = (const float*)d_in[9];
    const float* h_whh_f = (const float*)d_in[10];
    const float* h_bih_f = (const float*)d_in[11];
    const float* h_bhh_f = (const float*)d_in[12];
    const float* h_wih_b = (const float*)d_in[13];
    const float* h_whh_b = (const float*)d_in[14];
    const float* h_bih_b = (const float*)d_in[15];
    const float* h_bhh_b = (const float*)d_in[16];
    const float* conv_w  = (const float*)d_in[17];
    const float* conv_b  = (const float*)d_in[18];
    const float* bn_g    = (const float*)d_in[19];
    const float* bn_b    = (const float*)d_in[20];
    float* out = (float*)d_out;

    // d_out (302 MB) doubles as scratch before conv_bn rewrites all of it:
    //   bytes [0, 151 MB): xg buffer (bf16, 294912 x 256)
    //   bytes [226.5, 302 MB): v (f32 [B,H,W,64]) — vertical LSTM output
    const size_t v_elems = (size_t)Bn * Hn * Wn * 64;   // 18,874,368
    float* v_buf = out + ((size_t)out_size - v_elems);
    unsigned short* xgbuf = (unsigned short*)d_out;      // 150,994,944 bytes

    // workspace layout (~40 MB)
    unsigned short* hh = (unsigned short*)d_ws;                       // bf16 [B,H,W,64]
    char* wsb = (char*)d_ws;
    float* part = (float*)(wsb + 37748736);                           // 128 x 4160 f32
    float* M    = (float*)(wsb + 37748736 + 2129920);                 // 4160 f32
    float* Aarr = M + 4160;
    float* Barr = Aarr + 256;

    // vertical pass
    xg_kernel<1><<<3072, 512, 0, stream>>>(x, v_wih_f, v_bih_f, v_bhh_f,
                                           v_wih_b, v_bih_b, v_bhh_b, xgbuf);
    lstm_rec<1><<<1536, 256, 0, stream>>>(xgbuf, v_whh_f, v_whh_b, (void*)v_buf);
    // horizontal pass
    xg_kernel<0><<<3072, 512, 0, stream>>>(v_buf, h_wih_f, h_bih_f, h_bhh_f,
                                           h_wih_b, h_bih_b, h_bhh_b, xgbuf);
    lstm_rec<0><<<1536, 256, 0, stream>>>(xgbuf, h_whh_f, h_whh_b, (void*)hh);
    // conv + BN (affine-folded via Gram-matrix stats)
    gram_partial<<<GRAM_BLOCKS, 256, 0, stream>>>(hh, part);
    gram_reduce<<<17, 256, 0, stream>>>(part, M);
    stats_kernel<<<1, 256, 0, stream>>>(M, conv_w, conv_b, bn_g, bn_b, Aarr, Barr);
    conv_bn_kernel<<<3072, 512, 0, stream>>>(hh, conv_w, Aarr, Barr, out);
}